// Round 1
// baseline (228.171 us; speedup 1.0000x reference)
//
#include <hip/hip_runtime.h>
#include <math.h>

// 14-qubit batched statevector sim, one sample per workgroup, state in LDS.
// Circuit: RY(x_w) embed -> 4 x [RX(qp[l,w]) all wires; CNOT ring w->w+1] -> <Z_w> -> linear head.
//
// Fusion: wires grouped [0,5) [5,10) [10,14). Each thread holds a 2^M-amplitude
// register chunk; rotations + intra-group CNOTs run in registers. Cross-group
// CNOT(c,t) where only the control is external = uniform conditional swap.
// Wrap CNOT(13,0) is deferred to the next layer's first pass (ext-ctrl pre-op);
// at readout it is just a sign flip on z0.
// LDS pad i+(i>>5): strides 1/32/1024 all map to <=2 lanes per bank (free).

#define NQ 14
#define NSTATE (1 << NQ)
#define NLAYERS 4
#define NCLASSES 10
#define BLOCK 512
#define PADN (NSTATE + (NSTATE >> 5))   // 16896 floats per component

__device__ __forceinline__ int pidx(int i) { return i + (i >> 5); }

template<int LO, int M, bool IS_RX, int PRE_CTRL, int POST_CTRL, bool CHAIN>
__device__ __forceinline__ void run_pass(float* __restrict__ re, float* __restrict__ im,
                                         const float* __restrict__ cw,
                                         const float* __restrict__ sw)
{
  constexpr int KN  = 1 << M;
  constexpr int NCH = NSTATE >> M;
  float c[M], s[M];
#pragma unroll
  for (int j = 0; j < M; ++j) { c[j] = cw[j]; s[j] = sw[j]; }  // LDS broadcast reads

  for (int chunk = threadIdx.x; chunk < NCH; chunk += BLOCK) {
    const int low  = chunk & ((1 << LO) - 1);
    const int high = chunk >> LO;
    const int base = low | (high << (LO + M));
    float ar[KN], ai[KN];
#pragma unroll
    for (int k = 0; k < KN; ++k) {
      const int p = pidx(base + (k << LO));
      ar[k] = re[p];
      ai[k] = im[p];
    }
    // deferred CNOT(ext ctrl -> local bit 0), applied BEFORE rotations
    if constexpr (PRE_CTRL >= 0) {
      if ((base >> PRE_CTRL) & 1) {
#pragma unroll
        for (int k = 0; k < KN; k += 2) {
          float t = ar[k]; ar[k] = ar[k + 1]; ar[k + 1] = t;
          t = ai[k]; ai[k] = ai[k + 1]; ai[k + 1] = t;
        }
      }
    }
    // rotations on each local wire j
#pragma unroll
    for (int j = 0; j < M; ++j) {
#pragma unroll
      for (int k = 0; k < KN; ++k) {
        if ((k & (1 << j)) == 0) {
          const int k1 = k | (1 << j);
          const float r0 = ar[k], i0 = ai[k], r1 = ar[k1], i1 = ai[k1];
          if (IS_RX) {
            // [[c, -is],[-is, c]]
            ar[k]  = fmaf(c[j], r0,  s[j] * i1);
            ai[k]  = fmaf(c[j], i0, -s[j] * r1);
            ar[k1] = fmaf(c[j], r1,  s[j] * i0);
            ai[k1] = fmaf(c[j], i1, -s[j] * r0);
          } else {
            // RY [[c, -s],[s, c]]
            ar[k]  = fmaf(c[j], r0, -s[j] * r1);
            ai[k]  = fmaf(c[j], i0, -s[j] * i1);
            ar[k1] = fmaf(s[j], r0,  c[j] * r1);
            ai[k1] = fmaf(s[j], i0,  c[j] * i1);
          }
        }
      }
    }
    // CNOT with external control entering this group (ctrl -> local bit 0), AFTER rotations
    if constexpr (POST_CTRL >= 0) {
      if ((base >> POST_CTRL) & 1) {
#pragma unroll
        for (int k = 0; k < KN; k += 2) {
          float t = ar[k]; ar[k] = ar[k + 1]; ar[k + 1] = t;
          t = ai[k]; ai[k] = ai[k + 1]; ai[k + 1] = t;
        }
      }
    }
    // intra-group CNOT chain: ctrl local j -> tgt local j+1
    if constexpr (CHAIN) {
#pragma unroll
      for (int j = 0; j < M - 1; ++j) {
#pragma unroll
        for (int k = 0; k < KN; ++k) {
          if ((k & (1 << j)) != 0 && (k & (1 << (j + 1))) == 0) {
            const int k2 = k | (1 << (j + 1));
            float t = ar[k]; ar[k] = ar[k2]; ar[k2] = t;
            t = ai[k]; ai[k] = ai[k2]; ai[k2] = t;
          }
        }
      }
    }
#pragma unroll
    for (int k = 0; k < KN; ++k) {
      const int p = pidx(base + (k << LO));
      re[p] = ar[k];
      im[p] = ai[k];
    }
  }
}

__global__ __launch_bounds__(BLOCK) void qsim_kernel(
    const float* __restrict__ x, const float* __restrict__ qp,
    const float* __restrict__ fcw, const float* __restrict__ fcb,
    float* __restrict__ out)
{
  extern __shared__ float lds[];
  float* re    = lds;
  float* im    = lds + PADN;
  float* ryc   = im + PADN;                // 14
  float* rys   = ryc + NQ;                 // 14
  float* rxc   = rys + NQ;                 // 56
  float* rxs   = rxc + NLAYERS * NQ;       // 56
  float* zbuf  = rxs + NLAYERS * NQ;       // 14
  float* zpart = zbuf + NQ;                // (BLOCK/64)*14

  const int b   = blockIdx.x;
  const int tid = threadIdx.x;

  if (tid < NQ) {
    float sv, cv;
    sincosf(0.5f * x[b * NQ + tid], &sv, &cv);
    ryc[tid] = cv; rys[tid] = sv;
  } else if (tid >= 64 && tid < 64 + NLAYERS * NQ) {
    const int k = tid - 64;
    float sv, cv;
    sincosf(0.5f * qp[k], &sv, &cv);
    rxc[k] = cv; rxs[k] = sv;
  }
  for (int i = tid; i < NSTATE; i += BLOCK) {
    re[pidx(i)] = (i == 0) ? 1.0f : 0.0f;
    im[pidx(i)] = 0.0f;
  }
  __syncthreads();

  // RY embedding (3 sweeps)
  run_pass<0, 5, false, -1, -1, false>(re, im, ryc, rys);             __syncthreads();
  run_pass<5, 5, false, -1, -1, false>(re, im, ryc + 5, rys + 5);     __syncthreads();
  run_pass<10, 4, false, -1, -1, false>(re, im, ryc + 10, rys + 10);  __syncthreads();

  // 4 entangler layers, 3 sweeps each
  for (int l = 0; l < NLAYERS; ++l) {
    const float* lc = rxc + l * NQ;
    const float* ls = rxs + l * NQ;
    if (l == 0) run_pass<0, 5, true, -1, -1, true>(re, im, lc, ls);
    else        run_pass<0, 5, true, 13, -1, true>(re, im, lc, ls);   // deferred CNOT(13,0)
    __syncthreads();
    run_pass<5, 5, true, -1, 4, true>(re, im, lc + 5, ls + 5);        // CNOT(4,5) ext ctrl
    __syncthreads();
    run_pass<10, 4, true, -1, 9, true>(re, im, lc + 10, ls + 10);     // CNOT(9,10) ext ctrl
    __syncthreads();
  }

  // Readout. Pending CNOT(13,0): only permutes |amp|^2 within bit-0 pairs ->
  // equivalent to flipping the sign of z0 where bit13(base)==1.
  float zloc[NQ];
#pragma unroll
  for (int w = 0; w < NQ; ++w) zloc[w] = 0.f;

  for (int chunk = tid; chunk < (NSTATE >> 5); chunk += BLOCK) {
    const int base = chunk << 5;
    float ssum = 0.f;
    float sbit[5] = {0.f, 0.f, 0.f, 0.f, 0.f};
#pragma unroll
    for (int k = 0; k < 32; ++k) {
      const int p = pidx(base + k);
      const float r = re[p], q = im[p];
      const float pr = fmaf(r, r, q * q);
      ssum += pr;
#pragma unroll
      for (int j = 0; j < 5; ++j)
        if (k & (1 << j)) sbit[j] += pr;
    }
    float z0 = ssum - 2.f * sbit[0];
    if ((base >> 13) & 1) z0 = -z0;
    zloc[0] += z0;
#pragma unroll
    for (int j = 1; j < 5; ++j) zloc[j] += ssum - 2.f * sbit[j];
#pragma unroll
    for (int w = 5; w < NQ; ++w) zloc[w] += ((base >> w) & 1) ? -ssum : ssum;
  }

  // wave reduce (64 lanes), then per-wave partials in LDS
#pragma unroll
  for (int w = 0; w < NQ; ++w) {
#pragma unroll
    for (int off = 32; off > 0; off >>= 1)
      zloc[w] += __shfl_down(zloc[w], off, 64);
  }
  const int wave = tid >> 6, lane = tid & 63;
  if (lane == 0) {
#pragma unroll
    for (int w = 0; w < NQ; ++w) zpart[wave * NQ + w] = zloc[w];
  }
  __syncthreads();
  if (tid < NQ) {
    float acc = 0.f;
#pragma unroll
    for (int v = 0; v < BLOCK / 64; ++v) acc += zpart[v * NQ + tid];
    zbuf[tid] = acc;
  }
  __syncthreads();

  // linear head: logits[b,c] = fcb[c] + sum_w z[w] * fcw[c,w]
  if (tid < NCLASSES) {
    float acc = fcb[tid];
#pragma unroll
    for (int w = 0; w < NQ; ++w) acc = fmaf(zbuf[w], fcw[tid * NQ + w], acc);
    out[b * NCLASSES + tid] = acc;
  }
}

extern "C" void kernel_launch(void* const* d_in, const int* in_sizes, int n_in,
                              void* d_out, int out_size, void* d_ws, size_t ws_size,
                              hipStream_t stream) {
  const float* x   = (const float*)d_in[0];
  const float* qp  = (const float*)d_in[1];
  const float* fcw = (const float*)d_in[2];
  const float* fcb = (const float*)d_in[3];
  float* out = (float*)d_out;
  const int B = in_sizes[0] / NQ;

  const size_t shmem =
      (size_t)(2 * PADN + 2 * NQ + 2 * NLAYERS * NQ + NQ + (BLOCK / 64) * NQ) * sizeof(float);
  // 136 KB dynamic LDS > 64 KB default cap: raise the limit (host-side, capture-safe).
  (void)hipFuncSetAttribute((const void*)qsim_kernel,
                            hipFuncAttributeMaxDynamicSharedMemorySize, (int)shmem);
  qsim_kernel<<<B, BLOCK, shmem, stream>>>(x, qp, fcw, fcb, out);
}

// Round 2
// 145.237 us; speedup vs baseline: 1.5710x; 1.5710x over previous
//
#include <hip/hip_runtime.h>
#include <hip/hip_fp16.h>
#include <math.h>

// 14-qubit batched statevector sim, one sample per workgroup, state in LDS as
// packed __half2 (re=low, im=high) -> 64 KB state, 2 blocks/CU, pk-fp16 gates.
//
// Circuit: RY(x_w) embed -> 4 x [RX(qp[l,w]) all wires; CNOT ring] -> <Z_w> -> linear head.
// Fusion: wire groups [0,5) [5,10) [10,14); rotations + intra-group CNOTs in
// registers; cross-group CNOT = uniform conditional register swap; wrap
// CNOT(13,0) deferred (ext-ctrl pre-op next layer / sign trick at readout).
// Extra fusion vs R1: |0> init folded into first RY pass (no init sweep, no
// first read); readout folded into last group-C pass (no final write, no
// readout read). 28 half-state sweeps of 64 KB vs R1's 32 of 128 KB.
//
// LDS pad i+(i>>5) on 4B elements: access strides 1 / 33 / 1056 words all map
// to <=2 lanes/bank for a 64-lane wave (2-way is free on gfx950, m136).

#define NQ 14
#define NSTATE (1 << NQ)
#define NLAYERS 4
#define NCLASSES 10
#define BLOCK 512
#define PADN (NSTATE + (NSTATE >> 5))   // 16896 half2 elements = 66 KB

template<int LO, int M, int STEP, bool IS_RX, bool INIT, int PRE_CTRL, int POST_CTRL, bool CHAIN, bool FINAL>
__device__ __forceinline__ void run_pass(__half2* __restrict__ st,
                                         const __half2* __restrict__ cw,
                                         const __half2* __restrict__ sw,
                                         float* __restrict__ zloc)
{
  constexpr int KN  = 1 << M;
  constexpr int NCH = NSTATE >> M;
  __half2 c[M], s[M];
#pragma unroll
  for (int j = 0; j < M; ++j) { c[j] = cw[j]; s[j] = sw[j]; }  // LDS broadcast

  for (int chunk = threadIdx.x; chunk < NCH; chunk += BLOCK) {
    const int low   = chunk & ((1 << LO) - 1);
    const int high  = chunk >> LO;
    const int base  = low | (high << (LO + M));
    const int pbase = base + (base >> 5);   // padded; a[k] lives at pbase + k*STEP
    __half2 a[KN];
    if constexpr (INIT) {
#pragma unroll
      for (int k = 0; k < KN; ++k) a[k] = __floats2half2_rn(0.f, 0.f);
      if (chunk == 0) a[0] = __floats2half2_rn(1.f, 0.f);
    } else {
#pragma unroll
      for (int k = 0; k < KN; ++k) a[k] = st[pbase + k * STEP];
    }
    // deferred CNOT(ext ctrl -> local bit 0), BEFORE rotations
    if constexpr (PRE_CTRL >= 0) {
      if ((base >> PRE_CTRL) & 1) {
#pragma unroll
        for (int k = 0; k < KN; k += 2) { __half2 t = a[k]; a[k] = a[k + 1]; a[k + 1] = t; }
      }
    }
    // rotations on local wires. RX: s[j]=(sin,-sin), a0' = c*a0 + sm*swap(a1).
    // RY: s[j]=(sin,sin), a0' = c*a0 - s*a1 ; a1' = s*a0 + c*a1.
#pragma unroll
    for (int j = 0; j < M; ++j) {
#pragma unroll
      for (int k = 0; k < KN; ++k) {
        if ((k & (1 << j)) == 0) {
          const int k1 = k | (1 << j);
          const __half2 a0 = a[k], a1 = a[k1];
          if constexpr (IS_RX) {
            a[k]  = __hfma2(s[j], __lowhigh2highlow(a1), __hmul2(c[j], a0));
            a[k1] = __hfma2(s[j], __lowhigh2highlow(a0), __hmul2(c[j], a1));
          } else {
            a[k]  = __hsub2(__hmul2(c[j], a0), __hmul2(s[j], a1));
            a[k1] = __hfma2(s[j], a0, __hmul2(c[j], a1));
          }
        }
      }
    }
    // CNOT with external control entering this group, AFTER rotations
    if constexpr (POST_CTRL >= 0) {
      if ((base >> POST_CTRL) & 1) {
#pragma unroll
        for (int k = 0; k < KN; k += 2) { __half2 t = a[k]; a[k] = a[k + 1]; a[k + 1] = t; }
      }
    }
    // intra-group CNOT chain: local j -> j+1
    if constexpr (CHAIN) {
#pragma unroll
      for (int j = 0; j < M - 1; ++j) {
#pragma unroll
        for (int k = 0; k < KN; ++k) {
          if ((k & (1 << j)) != 0 && (k & (1 << (j + 1))) == 0) {
            const int k2 = k | (1 << (j + 1));
            __half2 t = a[k]; a[k] = a[k2]; a[k2] = t;
          }
        }
      }
    }
    if constexpr (FINAL) {
      // group C (LO=10): k bits 0..3 = wires 10..13; base bits = wires 0..9.
      // Pending CNOT(13,0): z0 contrib per amp = (-1)^(bit0 ^ bit13) * p.
      float ssum = 0.f, sb0 = 0.f, sb1 = 0.f, sb2 = 0.f, sb3 = 0.f;
#pragma unroll
      for (int k = 0; k < KN; ++k) {
        const float2 v = __half22float2(a[k]);
        const float p = fmaf(v.x, v.x, v.y * v.y);
        ssum += p;
        if (k & 1) sb0 += p;
        if (k & 2) sb1 += p;
        if (k & 4) sb2 += p;
        if (k & 8) sb3 += p;
      }
      zloc[10] += ssum - 2.f * sb0;
      zloc[11] += ssum - 2.f * sb1;
      zloc[12] += ssum - 2.f * sb2;
      zloc[13] += ssum - 2.f * sb3;
      const float z0 = ssum - 2.f * sb3;
      zloc[0] += (base & 1) ? -z0 : z0;
#pragma unroll
      for (int w = 1; w < 10; ++w) zloc[w] += ((base >> w) & 1) ? -ssum : ssum;
    } else {
#pragma unroll
      for (int k = 0; k < KN; ++k) st[pbase + k * STEP] = a[k];
    }
  }
}

__global__ __launch_bounds__(BLOCK) void qsim_kernel(
    const float* __restrict__ x, const float* __restrict__ qp,
    const float* __restrict__ fcw, const float* __restrict__ fcb,
    float* __restrict__ out)
{
  extern __shared__ unsigned char smem[];
  __half2* st  = (__half2*)smem;
  __half2* ryc = st + PADN;                 // 14
  __half2* rys = ryc + NQ;                  // 14
  __half2* rxc = rys + NQ;                  // 56
  __half2* rxs = rxc + NLAYERS * NQ;        // 56
  float*   zbuf  = (float*)(rxs + NLAYERS * NQ);  // 14
  float*   zpart = zbuf + NQ;               // (BLOCK/64)*14

  const int b   = blockIdx.x;
  const int tid = threadIdx.x;

  if (tid < NQ) {
    float sv, cv;
    sincosf(0.5f * x[b * NQ + tid], &sv, &cv);
    ryc[tid] = __floats2half2_rn(cv, cv);
    rys[tid] = __floats2half2_rn(sv, sv);
  } else if (tid >= 64 && tid < 64 + NLAYERS * NQ) {
    const int k = tid - 64;
    float sv, cv;
    sincosf(0.5f * qp[k], &sv, &cv);
    rxc[k] = __floats2half2_rn(cv, cv);
    rxs[k] = __floats2half2_rn(sv, -sv);   // (s,-s): a' = c*a + sm*swap(partner)
  }
  __syncthreads();

  // RY embedding; pass A also constructs |0..0> (no init sweep)
  run_pass<0, 5, 1,    false, true,  -1, -1, false, false>(st, ryc,      rys,      nullptr); __syncthreads();
  run_pass<5, 5, 33,   false, false, -1, -1, false, false>(st, ryc + 5,  rys + 5,  nullptr); __syncthreads();
  run_pass<10, 4, 1056,false, false, -1, -1, false, false>(st, ryc + 10, rys + 10, nullptr); __syncthreads();

  float zloc[NQ];
#pragma unroll
  for (int w = 0; w < NQ; ++w) zloc[w] = 0.f;

#pragma unroll
  for (int l = 0; l < NLAYERS; ++l) {
    const __half2* lc = rxc + l * NQ;
    const __half2* ls = rxs + l * NQ;
    if (l == 0) run_pass<0, 5, 1, true, false, -1, -1, true, false>(st, lc, ls, nullptr);
    else        run_pass<0, 5, 1, true, false, 13, -1, true, false>(st, lc, ls, nullptr); // deferred CNOT(13,0)
    __syncthreads();
    run_pass<5, 5, 33, true, false, -1, 4, true, false>(st, lc + 5, ls + 5, nullptr);     // CNOT(4,5) ext ctrl
    __syncthreads();
    if (l < NLAYERS - 1) {
      run_pass<10, 4, 1056, true, false, -1, 9, true, false>(st, lc + 10, ls + 10, nullptr); // CNOT(9,10)
      __syncthreads();
    } else {
      // last pass: fused readout, no writeback
      run_pass<10, 4, 1056, true, false, -1, 9, true, true>(st, lc + 10, ls + 10, zloc);
    }
  }

  // wave reduce (64 lanes) then per-wave partials in LDS
#pragma unroll
  for (int w = 0; w < NQ; ++w) {
#pragma unroll
    for (int off = 32; off > 0; off >>= 1)
      zloc[w] += __shfl_down(zloc[w], off, 64);
  }
  const int wave = tid >> 6, lane = tid & 63;
  if (lane == 0) {
#pragma unroll
    for (int w = 0; w < NQ; ++w) zpart[wave * NQ + w] = zloc[w];
  }
  __syncthreads();
  if (tid < NQ) {
    float acc = 0.f;
#pragma unroll
    for (int v = 0; v < BLOCK / 64; ++v) acc += zpart[v * NQ + tid];
    zbuf[tid] = acc;
  }
  __syncthreads();

  // linear head
  if (tid < NCLASSES) {
    float acc = fcb[tid];
#pragma unroll
    for (int w = 0; w < NQ; ++w) acc = fmaf(zbuf[w], fcw[tid * NQ + w], acc);
    out[b * NCLASSES + tid] = acc;
  }
}

extern "C" void kernel_launch(void* const* d_in, const int* in_sizes, int n_in,
                              void* d_out, int out_size, void* d_ws, size_t ws_size,
                              hipStream_t stream) {
  const float* x   = (const float*)d_in[0];
  const float* qp  = (const float*)d_in[1];
  const float* fcw = (const float*)d_in[2];
  const float* fcb = (const float*)d_in[3];
  float* out = (float*)d_out;
  const int B = in_sizes[0] / NQ;

  const size_t shmem = (size_t)PADN * sizeof(__half2)
                     + (size_t)(2 * NQ + 2 * NLAYERS * NQ) * sizeof(__half2)
                     + (size_t)(NQ + (BLOCK / 64) * NQ) * sizeof(float);
  // ~67 KB dynamic LDS > 64 KB default cap: raise the limit (capture-safe).
  (void)hipFuncSetAttribute((const void*)qsim_kernel,
                            hipFuncAttributeMaxDynamicSharedMemorySize, (int)shmem);
  qsim_kernel<<<B, BLOCK, shmem, stream>>>(x, qp, fcw, fcb, out);
}